// Round 12
// baseline (4895.048 us; speedup 1.0000x reference)
//
#include <hip/hip_runtime.h>
#include <math.h>

#define BB 64
#define TT 512
#define FF 32
#define HH 512
#define OO 680

typedef _Float16 half8 __attribute__((ext_vector_type(8)));
typedef float f32x4 __attribute__((ext_vector_type(4)));

// ---- ws layout: act slabs in MFMA-B-fragment tile order, ping-pong ----
// tile(ks,bfrag) = 1KB; lane l owns 16B at l*16 holding elements
// (k = ks*32 + (l>>4)*8 + j, batch = bfrag*16 + (l&15)), j=0..7.
#define H1SLAB 65536u
#define C1SLAB 65536u
#define H2SLAB 90112u                  // 22 k-tiles (680 cols zero-padded to 704)
#define H1S_OFF 0u
#define C1S_OFF 131072u
#define H2S_OFF 262144u
#define BAR_OFF 442368u
#define MEMSET_BYTES 444928u

#define L1B  16                        // blocks [0,16): L1, 32 cols each
#define NBLK 59                        // blocks [16,59): L2, 16 cols each
#define LDS_BYTES 159744u              // L2: 152KB weight slab + 4KB exchange

__device__ __forceinline__ float sigf(float x) { return 1.f / (1.f + expf(-x)); }

__device__ __forceinline__ unsigned long long aload8(const void* p) {
    return __hip_atomic_load((const unsigned long long*)p, __ATOMIC_RELAXED, __HIP_MEMORY_SCOPE_AGENT);
}
__device__ __forceinline__ void astore8(void* p, unsigned long long v) {
    __hip_atomic_store((unsigned long long*)p, v, __ATOMIC_RELAXED, __HIP_MEMORY_SCOPE_AGENT);
}
__device__ __forceinline__ half8 ld_act(const char* p) {
    union { unsigned long long u[2]; half8 h; } t;
    t.u[0] = aload8(p); t.u[1] = aload8(p + 8);
    return t.h;
}
__device__ __forceinline__ unsigned pack2h(float a, float b) {
    union { _Float16 h[2]; unsigned u; } t;
    t.h[0] = (_Float16)a; t.h[1] = (_Float16)b; return t.u;
}
__device__ __forceinline__ unsigned long long pack4h(float a, float b, float c, float d) {
    union { _Float16 h[4]; unsigned long long u; } t;
    t.h[0] = (_Float16)a; t.h[1] = (_Float16)b; t.h[2] = (_Float16)c; t.h[3] = (_Float16)d;
    return t.u;
}

// One-hop grid barrier. Monotonic arrival counters (no reset stores): group x's
// gen-th epoch completes when cnt[x] reaches gen*gsz; the last arriver stores
// groupflag[x]=gen; every leader polls all 8 group flags in parallel.
// No fences anywhere (all cross-block data moves at the coherence point).
__device__ __forceinline__ void gridbar(unsigned* bar, int blk, unsigned gen) {
    __syncthreads();   // [HIP-compiler] drains each wave's stores before s_barrier
    if (threadIdx.x == 0) {
        const int x = blk & 7;
        const unsigned gsz = (x < 3) ? 8u : 7u;   // 59 = 3*8 + 5*7
        unsigned* cnt = bar + x * 32;
        const unsigned a = __hip_atomic_fetch_add(cnt, 1u, __ATOMIC_RELAXED, __HIP_MEMORY_SCOPE_AGENT);
        if (a == gen * gsz - 1u)
            __hip_atomic_store(bar + 256 + x * 32, gen, __ATOMIC_RELAXED, __HIP_MEMORY_SCOPE_AGENT);
        for (;;) {
            unsigned ok = 1u;
            #pragma unroll
            for (int r = 0; r < 8; ++r)
                ok &= (__hip_atomic_load(bar + 256 + r * 32, __ATOMIC_RELAXED, __HIP_MEMORY_SCOPE_AGENT) >= gen) ? 1u : 0u;
            if (ok) break;
            __builtin_amdgcn_s_sleep(1);
        }
    }
    __syncthreads();
}

#define MFMA4(B, AT) \
    acc0 = __builtin_amdgcn_mfma_f32_16x16x32_f16(*(const half8*)((AT)       ), (B), acc0, 0, 0, 0); \
    acc1 = __builtin_amdgcn_mfma_f32_16x16x32_f16(*(const half8*)((AT) + 1024), (B), acc1, 0, 0, 0); \
    acc2 = __builtin_amdgcn_mfma_f32_16x16x32_f16(*(const half8*)((AT) + 2048), (B), acc2, 0, 0, 0); \
    acc3 = __builtin_amdgcn_mfma_f32_16x16x32_f16(*(const half8*)((AT) + 3072), (B), acc3, 0, 0, 0);

// Persistent MFMA kernel, 59 blocks x 512 threads, weights LDS-resident.
__global__ __launch_bounds__(512, 1)
void rnn_mfma(const float* __restrict__ data,
    const float* __restrict__ Wih1, const float* __restrict__ Whh1,
    const float* __restrict__ bih1, const float* __restrict__ bhh1,
    const float* __restrict__ Wih2, const float* __restrict__ Whh2,
    const float* __restrict__ bih2, const float* __restrict__ bhh2,
    char* __restrict__ wsb, float* __restrict__ out)
{
    extern __shared__ char lds[];
    const int tid = threadIdx.x, wv = tid >> 6, l = tid & 63;
    const int hi = l >> 4, lo = l & 15;
    const int blk = blockIdx.x;
    const bool isL1 = blk < L1B;
    unsigned* bar = (unsigned*)(wsb + BAR_OFF);
    const int bfrag = wv & 3;
    const int b = bfrag * 16 + lo;
    const int c0 = isL1 ? blk * 32 : (blk - L1B) * 16;

    // ---- one-time: convert this block's weight slab fp32->fp16 into LDS ----
    if (isL1) {
        for (int u = tid; u < 136 * 256; u += 512) {
            const int tile = u >> 8, w = u & 255;
            const int ll = w >> 2, jj = w & 3;
            const int ks = tile >> 3, rest = tile & 7;
            const int gate = rest >> 1, chi = rest & 1;
            const int col = c0 + chi * 16 + (ll & 15);
            const int row = gate * HH + col;
            const int kk = ks * 32 + (ll >> 4) * 8 + jj * 2;
            const float v0 = (kk < FF)     ? Wih1[(size_t)row * FF + kk]     : Whh1[(size_t)row * HH + kk - FF];
            const float v1 = (kk + 1 < FF) ? Wih1[(size_t)row * FF + kk + 1] : Whh1[(size_t)row * HH + kk + 1 - FF];
            ((unsigned*)lds)[tile * 256 + w] = pack2h(v0, v1);
        }
    } else {
        for (int u = tid; u < 152 * 256; u += 512) {
            const int tile = u >> 8, w = u & 255;
            const int ll = w >> 2, jj = w & 3;
            const int ks = tile >> 2, gate = tile & 3;
            const int col = c0 + (ll & 15);
            const int kk = ks * 32 + (ll >> 4) * 8 + jj * 2;
            float v0 = 0.f, v1 = 0.f;
            if (col < OO) {
                if (kk < HH) v0 = Wih2[((size_t)gate * OO + col) * HH + kk];
                else if (kk < 1192) v0 = Whh2[((size_t)gate * OO + col) * OO + kk - HH];
                if (kk + 1 < HH) v1 = Wih2[((size_t)gate * OO + col) * HH + kk + 1];
                else if (kk + 1 < 1192) v1 = Whh2[((size_t)gate * OO + col) * OO + kk + 1 - HH];
            }
            ((unsigned*)lds)[tile * 256 + w] = pack2h(v0, v1);
        }
    }
    __syncthreads();

    // ---- bias hoist (epilogue waves) ----
    float bs[2][4][4];
    if (wv < 4) {
        if (isL1) {
            #pragma unroll
            for (int chi = 0; chi < 2; ++chi)
                #pragma unroll
                for (int r = 0; r < 4; ++r) {
                    const int col = c0 + chi * 16 + hi * 4 + r;
                    #pragma unroll
                    for (int g = 0; g < 4; ++g)
                        bs[chi][r][g] = bih1[g * HH + col] + bhh1[g * HH + col];
                }
        } else {
            #pragma unroll
            for (int r = 0; r < 4; ++r) {
                const int col = c0 + hi * 4 + r;
                const bool ok = col < OO;
                #pragma unroll
                for (int g = 0; g < 4; ++g)
                    bs[0][r][g] = ok ? (bih2[g * OO + col] + bhh2[g * OO + col]) : 0.f;
            }
        }
    }

    const int gh = wv >> 2;                 // L1: gate-pair; L2: K-half
    float cr[8] = {0.f,0.f,0.f,0.f,0.f,0.f,0.f,0.f};
    f32x4 (*part1)[4][64] = (f32x4(*)[4][64])(lds + 136 * 1024);
    f32x4* part2 = (f32x4*)(lds + 152 * 1024);

    // deferred out-store state (L2 epilogue waves): issued at next iteration's
    // start so the HBM ack drains behind compute, not in the pre-barrier wait.
    f32x4 pend = {0,0,0,0};
    float* pendP = nullptr;

    for (int s = 0; s <= TT; ++s) {
        const int A = s & 1, Bx = A ^ 1;
        const bool active = isL1 ? (s < TT) : (s >= 1);
        f32x4 acc0 = {0,0,0,0}, acc1 = {0,0,0,0}, acc2 = {0,0,0,0}, acc3 = {0,0,0,0};

        if (active) {
            if (isL1) {
                {   // k-step 0: x from data (fp32 -> fp16 B fragment)
                    const float* xp = data + (size_t)b * (TT * FF) + (size_t)s * FF + hi * 8;
                    const float4 xa = *(const float4*)xp;
                    const float4 xb = *(const float4*)(xp + 4);
                    half8 bxf;
                    bxf[0] = (_Float16)xa.x; bxf[1] = (_Float16)xa.y;
                    bxf[2] = (_Float16)xa.z; bxf[3] = (_Float16)xa.w;
                    bxf[4] = (_Float16)xb.x; bxf[5] = (_Float16)xb.y;
                    bxf[6] = (_Float16)xb.z; bxf[7] = (_Float16)xb.w;
                    const char* at = lds + (size_t)(gh * 4) * 1024 + (size_t)l * 16;
                    MFMA4(bxf, at);
                }
                const char* h1p = wsb + H1S_OFF + (size_t)A * H1SLAB + (size_t)l * 16;
                #pragma unroll
                for (int ks = 1; ks <= 16; ++ks) {
                    const half8 bf = ld_act(h1p + (size_t)(((ks - 1) * 4 + bfrag)) * 1024);
                    const char* at = lds + (size_t)(ks * 8 + gh * 4) * 1024 + (size_t)l * 16;
                    MFMA4(bf, at);
                }
            } else {
                if (gh == 0) {
                    // flush last iteration's out-store first (ack hides behind MFMA)
                    if (pendP) { __builtin_nontemporal_store(pend, (f32x4*)pendP); pendP = nullptr; }
                    const char* c1p = wsb + C1S_OFF + (size_t)A * C1SLAB + (size_t)l * 16;
                    #pragma unroll
                    for (int ks = 0; ks < 16; ++ks) {
                        const half8 bf = ld_act(c1p + (size_t)(ks * 4 + bfrag) * 1024);
                        const char* at = lds + (size_t)ks * 4096 + (size_t)l * 16;
                        MFMA4(bf, at);
                    }
                    const char* h2p = wsb + H2S_OFF + (size_t)Bx * H2SLAB + (size_t)l * 16;
                    #pragma unroll
                    for (int ks = 16; ks < 19; ++ks) {
                        const half8 bf = ld_act(h2p + (size_t)((ks - 16) * 4 + bfrag) * 1024);
                        const char* at = lds + (size_t)ks * 4096 + (size_t)l * 16;
                        MFMA4(bf, at);
                    }
                } else {
                    const char* h2p = wsb + H2S_OFF + (size_t)Bx * H2SLAB + (size_t)l * 16;
                    #pragma unroll
                    for (int ks = 19; ks < 38; ++ks) {
                        const half8 bf = ld_act(h2p + (size_t)((ks - 16) * 4 + bfrag) * 1024);
                        const char* at = lds + (size_t)ks * 4096 + (size_t)l * 16;
                        MFMA4(bf, at);
                    }
                }
            }
        }

        if (isL1) {
            if (active) {
                if (wv >= 4) {
                    part1[wv - 4][0][l] = acc0; part1[wv - 4][1][l] = acc1;
                    part1[wv - 4][2][l] = acc2; part1[wv - 4][3][l] = acc3;
                }
                __syncthreads();
                if (wv < 4) {
                    #pragma unroll
                    for (int chi = 0; chi < 2; ++chi) {
                        const f32x4 o0 = (chi == 0) ? acc0 : acc1;   // gate i
                        const f32x4 o1 = (chi == 0) ? acc2 : acc3;   // gate f
                        const f32x4 p0 = part1[wv][chi][l];          // gate g
                        const f32x4 p1 = part1[wv][2 + chi][l];      // gate o
                        float cn[4], hn[4];
                        #pragma unroll
                        for (int r = 0; r < 4; ++r) {
                            const float ig = sigf(o0[r] + bs[chi][r][0]);
                            const float fg = sigf(o1[r] + bs[chi][r][1]);
                            const float gg = tanhf(p0[r] + bs[chi][r][2]);
                            const float og = sigf(p1[r] + bs[chi][r][3]);
                            const float c = fg * cr[chi * 4 + r] + ig * gg;
                            cr[chi * 4 + r] = c;
                            cn[r] = c; hn[r] = og * tanhf(c);
                        }
                        const int cc = c0 + chi * 16 + hi * 4;
                        const size_t aoff = (size_t)(((cc >> 5) * 4 + wv)) * 1024
                                          + (size_t)((((cc >> 3) & 3) * 16 + lo)) * 16
                                          + (size_t)((hi & 1) * 8);
                        astore8(wsb + H1S_OFF + (size_t)Bx * H1SLAB + aoff, pack4h(hn[0], hn[1], hn[2], hn[3]));
                        astore8(wsb + C1S_OFF + (size_t)Bx * C1SLAB + aoff, pack4h(cn[0], cn[1], cn[2], cn[3]));
                    }
                }
            }
        } else {
            if (active) {
                f32x4 pr0 = {0,0,0,0}, pr1 = {0,0,0,0}, pr2 = {0,0,0,0}, pr3 = {0,0,0,0};
                if (wv >= 4) part2[(wv - 4) * 64 + l] = acc0;
                __syncthreads();
                if (wv < 4) pr0 = part2[wv * 64 + l];
                __syncthreads();
                if (wv >= 4) part2[(wv - 4) * 64 + l] = acc1;
                __syncthreads();
                if (wv < 4) pr1 = part2[wv * 64 + l];
                __syncthreads();
                if (wv >= 4) part2[(wv - 4) * 64 + l] = acc2;
                __syncthreads();
                if (wv < 4) pr2 = part2[wv * 64 + l];
                __syncthreads();
                if (wv >= 4) part2[(wv - 4) * 64 + l] = acc3;
                __syncthreads();
                if (wv < 4) pr3 = part2[wv * 64 + l];
                if (wv < 4) {
                    const int u = s - 1;
                    float cn[4], hn[4];
                    #pragma unroll
                    for (int r = 0; r < 4; ++r) {
                        const float ig = sigf(acc0[r] + pr0[r] + bs[0][r][0]);
                        const float fg = sigf(acc1[r] + pr1[r] + bs[0][r][1]);
                        const float gg = tanhf(acc2[r] + pr2[r] + bs[0][r][2]);
                        const float og = sigf(acc3[r] + pr3[r] + bs[0][r][3]);
                        const float c = fg * cr[r] + ig * gg;
                        cr[r] = c;
                        cn[r] = c; hn[r] = og * tanhf(c);
                    }
                    const int cc = c0 + hi * 4;
                    if (cc < OO) {
                        pend[0] = cn[0]; pend[1] = cn[1]; pend[2] = cn[2]; pend[3] = cn[3];
                        pendP = out + (size_t)b * (TT * OO) + (size_t)u * OO + cc;
                        const size_t aoff = (size_t)(((cc >> 5) * 4 + wv)) * 1024
                                          + (size_t)((((cc >> 3) & 3) * 16 + lo)) * 16
                                          + (size_t)((hi & 1) * 8);
                        astore8(wsb + H2S_OFF + (size_t)A * H2SLAB + aoff, pack4h(hn[0], hn[1], hn[2], hn[3]));
                    }
                }
            }
        }
        gridbar(bar, blk, (unsigned)(s + 1));
    }

    // final deferred out-store (u = TT-1)
    if (!isL1 && wv < 4 && pendP)
        __builtin_nontemporal_store(pend, (f32x4*)pendP);
}

extern "C" void kernel_launch(void* const* d_in, const int* in_sizes, int n_in,
                              void* d_out, int out_size, void* d_ws, size_t ws_size,
                              hipStream_t stream)
{
    const float* data = (const float*)d_in[0];
    const float* Wih1 = (const float*)d_in[1];
    const float* Whh1 = (const float*)d_in[2];
    const float* bih1 = (const float*)d_in[3];
    const float* bhh1 = (const float*)d_in[4];
    const float* Wih2 = (const float*)d_in[5];
    const float* Whh2 = (const float*)d_in[6];
    const float* bih2 = (const float*)d_in[7];
    const float* bhh2 = (const float*)d_in[8];
    float* out = (float*)d_out;
    char* wsb  = (char*)d_ws;

    hipFuncSetAttribute((const void*)rnn_mfma, hipFuncAttributeMaxDynamicSharedMemorySize, (int)LDS_BYTES);
    hipMemsetAsync(wsb, 0, MEMSET_BYTES, stream);
    rnn_mfma<<<NBLK, 512, LDS_BYTES, stream>>>(data,
                                               Wih1, Whh1, bih1, bhh1,
                                               Wih2, Whh2, bih2, bhh2,
                                               wsb, out);
}

// Round 13
// 4495.375 us; speedup vs baseline: 1.0889x; 1.0889x over previous
//
#include <hip/hip_runtime.h>
#include <math.h>

#define BB 64
#define TT 512
#define FF 32
#define HH 512
#define OO 680

typedef _Float16 half8 __attribute__((ext_vector_type(8)));
typedef float f32x4 __attribute__((ext_vector_type(4)));

// ---- ws layout: act slabs in MFMA-B-fragment tile order ----
// tile(ks,bfrag) = 1KB; lane l owns 16B at l*16: k = ks*32+(l>>4)*8+j, batch = bfrag*16+(l&15).
#define H1SLAB 65536u
#define C1SLAB 65536u
#define H2SLAB 90112u                  // 22 k-tiles (680 cols zero-padded to 704)
#define H1S_OFF 0u                     // 2 buffers (ping-pong, L1-internal)
#define C1S_OFF 131072u                // 4-deep ring (L1 -> L2, decoupled)
#define H2S_OFF 393216u                // 2 buffers (ping-pong, L2-internal)
#define BAR_OFF 573440u
#define MEMSET_BYTES 576000u

#define L1B  16                        // blocks [0,16): L1, 32 cols each
#define NBLK 59                        // blocks [16,59): L2, 16 cols each
#define LDS_BYTES 155648u              // L2 weight slab 152KB (L1 uses 136KB)

// bar word offsets: counters on distinct 128B lines, flags packed per domain
#define L1CNT(g) ((g)*32)              // g=0..1, 8 blocks each
#define L1FLG    64                    // 2 dwords, one line
#define L2CNT(g) (96 + (g)*32)         // g=0..7
#define L2FLG    352                   // 8 dwords, one line

__device__ __forceinline__ float sigf(float x) { return 1.f / (1.f + expf(-x)); }

__device__ __forceinline__ unsigned long long aload8(const void* p) {
    return __hip_atomic_load((const unsigned long long*)p, __ATOMIC_RELAXED, __HIP_MEMORY_SCOPE_AGENT);
}
__device__ __forceinline__ void astore8(void* p, unsigned long long v) {
    __hip_atomic_store((unsigned long long*)p, v, __ATOMIC_RELAXED, __HIP_MEMORY_SCOPE_AGENT);
}
__device__ __forceinline__ void astore32(unsigned* p, unsigned v) {
    __hip_atomic_store(p, v, __ATOMIC_RELAXED, __HIP_MEMORY_SCOPE_AGENT);
}
__device__ __forceinline__ half8 ld_act(const char* p) {
    union { unsigned long long u[2]; half8 h; } t;
    t.u[0] = aload8(p); t.u[1] = aload8(p + 8);
    return t.h;
}
__device__ __forceinline__ unsigned pack2h(float a, float b) {
    union { _Float16 h[2]; unsigned u; } t;
    t.h[0] = (_Float16)a; t.h[1] = (_Float16)b; return t.u;
}
__device__ __forceinline__ unsigned long long pack4h(float a, float b, float c, float d) {
    union { _Float16 h[4]; unsigned long long u; } t;
    t.h[0] = (_Float16)a; t.h[1] = (_Float16)b; t.h[2] = (_Float16)c; t.h[3] = (_Float16)d;
    return t.u;
}
__device__ __forceinline__ unsigned minL1(const unsigned* bar) {
    const unsigned long long v = aload8(bar + L1FLG);
    const unsigned a = (unsigned)v, b = (unsigned)(v >> 32);
    return a < b ? a : b;
}
__device__ __forceinline__ unsigned minL2(const unsigned* bar) {
    const unsigned long long v0 = aload8(bar + L2FLG);
    const unsigned long long v1 = aload8(bar + L2FLG + 2);
    const unsigned long long v2 = aload8(bar + L2FLG + 4);
    const unsigned long long v3 = aload8(bar + L2FLG + 6);
    unsigned m = (unsigned)v0;
    unsigned x;
    x = (unsigned)(v0 >> 32); m = x < m ? x : m;
    x = (unsigned)v1;         m = x < m ? x : m;
    x = (unsigned)(v1 >> 32); m = x < m ? x : m;
    x = (unsigned)v2;         m = x < m ? x : m;
    x = (unsigned)(v2 >> 32); m = x < m ? x : m;
    x = (unsigned)v3;         m = x < m ? x : m;
    x = (unsigned)(v3 >> 32); m = x < m ? x : m;
    return m;
}

// Persistent MFMA kernel, 59 blocks x 256 threads, weights LDS-resident.
// Split sync domains: L1 (16 blocks) ring-publishes c1, runs <=3 steps ahead;
// L2 (43 blocks) has the h2 recurrence. No mid-step exchange; lane-local epilogue.
__global__ __launch_bounds__(256, 1)
void rnn_mfma(const float* __restrict__ data,
    const float* __restrict__ Wih1, const float* __restrict__ Whh1,
    const float* __restrict__ bih1, const float* __restrict__ bhh1,
    const float* __restrict__ Wih2, const float* __restrict__ Whh2,
    const float* __restrict__ bih2, const float* __restrict__ bhh2,
    char* __restrict__ wsb, float* __restrict__ out)
{
    extern __shared__ char lds[];
    const int tid = threadIdx.x, wv = tid >> 6, l = tid & 63;
    const int hi = l >> 4, lo = l & 15;
    const int blk = blockIdx.x;
    unsigned* bar = (unsigned*)(wsb + BAR_OFF);
    const int bfrag = wv;              // wave = batch-fragment
    const int b = bfrag * 16 + lo;     // this lane's batch

    if (blk < L1B) {
        // ================= LAYER-1 BLOCK: 32 cols =================
        const int c0 = blk * 32;
        for (int u = tid; u < 136 * 256; u += 256) {   // weights -> LDS (fp16, A-frag tiles)
            const int tile = u >> 8, w = u & 255;
            const int ll = w >> 2, jj = w & 3;
            const int ks = tile >> 3, rest = tile & 7; // rest = gate*2 + chi
            const int gate = rest >> 1, chi = rest & 1;
            const int col = c0 + chi * 16 + (ll & 15);
            const int row = gate * HH + col;
            const int kk = ks * 32 + (ll >> 4) * 8 + jj * 2;
            const float v0 = (kk < FF)     ? Wih1[(size_t)row * FF + kk]     : Whh1[(size_t)row * HH + kk - FF];
            const float v1 = (kk + 1 < FF) ? Wih1[(size_t)row * FF + kk + 1] : Whh1[(size_t)row * HH + kk + 1 - FF];
            ((unsigned*)lds)[tile * 256 + w] = pack2h(v0, v1);
        }
        __syncthreads();

        float bs[2][4][4];
        #pragma unroll
        for (int chi = 0; chi < 2; ++chi)
            #pragma unroll
            for (int r = 0; r < 4; ++r) {
                const int col = c0 + chi * 16 + hi * 4 + r;
                #pragma unroll
                for (int g = 0; g < 4; ++g)
                    bs[chi][r][g] = bih1[g * HH + col] + bhh1[g * HH + col];
            }
        float cr[8] = {0.f,0.f,0.f,0.f,0.f,0.f,0.f,0.f};

        for (int s = 0; s < TT; ++s) {
            const int pr = s & 1;
            // x loads issued before the release spin (independent of recurrence)
            const float* xp = data + (size_t)b * (TT * FF) + (size_t)s * FF + hi * 8;
            const float4 xa = *(const float4*)xp;
            const float4 xb4 = *(const float4*)(xp + 4);
            // own-domain release: h1(s-1) ready
            if (s > 0) {
                if (tid == 0) { while (minL1(bar) < (unsigned)s) {} }
                __syncthreads();
            }
            half8 bx;
            bx[0] = (_Float16)xa.x; bx[1] = (_Float16)xa.y; bx[2] = (_Float16)xa.z; bx[3] = (_Float16)xa.w;
            bx[4] = (_Float16)xb4.x; bx[5] = (_Float16)xb4.y; bx[6] = (_Float16)xb4.z; bx[7] = (_Float16)xb4.w;

            f32x4 acc[8];
            #pragma unroll
            for (int a = 0; a < 8; ++a) acc[a] = (f32x4){0.f,0.f,0.f,0.f};
            #pragma unroll
            for (int a = 0; a < 8; ++a)
                acc[a] = __builtin_amdgcn_mfma_f32_16x16x32_f16(*(const half8*)(lds + (size_t)a * 1024 + (size_t)l * 16), bx, acc[a], 0, 0, 0);
            const char* h1p = wsb + H1S_OFF + (size_t)pr * H1SLAB + (size_t)l * 16;
            #pragma unroll
            for (int ks = 1; ks <= 16; ++ks) {
                const half8 bf = ld_act(h1p + (size_t)((ks - 1) * 4 + bfrag) * 1024);
                #pragma unroll
                for (int a = 0; a < 8; ++a)
                    acc[a] = __builtin_amdgcn_mfma_f32_16x16x32_f16(*(const half8*)(lds + (size_t)(ks * 8 + a) * 1024 + (size_t)l * 16), bf, acc[a], 0, 0, 0);
            }
            // throttle: don't overwrite the c1 ring slot L2 may still read
            if (s > 3) {
                if (tid == 0) { while (minL2(bar) < (unsigned)(s - 3)) {} }
                __syncthreads();
            }
            // lane-local epilogue (acc[gate*2+chi])
            char* h1w = wsb + H1S_OFF + (size_t)(pr ^ 1) * H1SLAB;
            char* c1w = wsb + C1S_OFF + (size_t)(s & 3) * C1SLAB;
            #pragma unroll
            for (int chi = 0; chi < 2; ++chi) {
                const int cc = c0 + chi * 16 + hi * 4;
                float cn[4], hn[4];
                #pragma unroll
                for (int r = 0; r < 4; ++r) {
                    const float ig = sigf(acc[0 + chi][r] + bs[chi][r][0]);
                    const float fg = sigf(acc[2 + chi][r] + bs[chi][r][1]);
                    const float gg = tanhf(acc[4 + chi][r] + bs[chi][r][2]);
                    const float og = sigf(acc[6 + chi][r] + bs[chi][r][3]);
                    const float c = fg * cr[chi * 4 + r] + ig * gg;
                    cr[chi * 4 + r] = c;
                    cn[r] = c; hn[r] = og * tanhf(c);
                }
                const size_t aoff = (size_t)((cc >> 5) * 4 + bfrag) * 1024
                                  + (size_t)((((cc >> 3) & 3) * 16 + lo)) * 16
                                  + (size_t)(cc & 7) * 2;
                astore8(h1w + aoff, pack4h(hn[0], hn[1], hn[2], hn[3]));
                astore8(c1w + aoff, pack4h(cn[0], cn[1], cn[2], cn[3]));
            }
            __syncthreads();   // drains all waves' stores
            if (tid == 0) {
                const int g = blk & 1;
                const unsigned e = (unsigned)(s + 1);
                const unsigned a2 = __hip_atomic_fetch_add(bar + L1CNT(g), 1u, __ATOMIC_RELAXED, __HIP_MEMORY_SCOPE_AGENT);
                if (a2 == e * 8u - 1u) astore32(bar + L1FLG + g, e);
            }
        }
    } else {
        // ================= LAYER-2 BLOCK: 16 cols =================
        const int idx = blk - L1B, c0 = idx * 16;
        const int grp = idx & 7;
        const unsigned gsz = (grp < 3) ? 6u : 5u;   // 43 = 3*6 + 5*5
        for (int u = tid; u < 152 * 256; u += 256) {   // weights -> LDS
            const int tile = u >> 8, w = u & 255;
            const int ll = w >> 2, jj = w & 3;
            const int ks = tile >> 2, gate = tile & 3;
            const int col = c0 + (ll & 15);
            const int kk = ks * 32 + (ll >> 4) * 8 + jj * 2;
            float v0 = 0.f, v1 = 0.f;
            if (col < OO) {
                if (kk < HH) v0 = Wih2[((size_t)gate * OO + col) * HH + kk];
                else if (kk < 1192) v0 = Whh2[((size_t)gate * OO + col) * OO + kk - HH];
                if (kk + 1 < HH) v1 = Wih2[((size_t)gate * OO + col) * HH + kk + 1];
                else if (kk + 1 < 1192) v1 = Whh2[((size_t)gate * OO + col) * OO + kk + 1 - HH];
            }
            ((unsigned*)lds)[tile * 256 + w] = pack2h(v0, v1);
        }
        __syncthreads();

        const int cc = c0 + hi * 4;
        float bs[4][4];
        #pragma unroll
        for (int r = 0; r < 4; ++r) {
            const int col = cc + r;
            const bool ok = col < OO;
            #pragma unroll
            for (int g = 0; g < 4; ++g)
                bs[r][g] = ok ? (bih2[g * OO + col] + bhh2[g * OO + col]) : 0.f;
        }
        float cr[4] = {0.f,0.f,0.f,0.f};

        for (int t = 1; t <= TT; ++t) {
            // (A) c1(t-1) ready? (L1 runs ahead -> normally instant)
            if (tid == 0) { while (minL1(bar) < (unsigned)t) {} }
            __syncthreads();
            // (B) issue ALL c1 loads; they fly during the h2 handoff wait below
            const char* c1p = wsb + C1S_OFF + (size_t)((t - 1) & 3) * C1SLAB + (size_t)l * 16;
            half8 bcs[16];
            #pragma unroll
            for (int ks = 0; ks < 16; ++ks) bcs[ks] = ld_act(c1p + (size_t)(ks * 4 + bfrag) * 1024);
            // (C) h2(t-2) handoff
            if (t > 1) {
                if (tid == 0) { while (minL2(bar) < (unsigned)(t - 1)) {} }
                __syncthreads();
            }
            // (D) h2 loads
            const char* h2p = wsb + H2S_OFF + (size_t)((t & 1) ^ 1) * H2SLAB + (size_t)l * 16;
            half8 bhs[22];
            #pragma unroll
            for (int ks = 0; ks < 22; ++ks) bhs[ks] = ld_act(h2p + (size_t)(ks * 4 + bfrag) * 1024);
            // (E) 4 gate chains over full K (c1 part first — data already here)
            f32x4 acc[4];
            #pragma unroll
            for (int g = 0; g < 4; ++g) acc[g] = (f32x4){0.f,0.f,0.f,0.f};
            #pragma unroll
            for (int ks = 0; ks < 16; ++ks) {
                #pragma unroll
                for (int g = 0; g < 4; ++g)
                    acc[g] = __builtin_amdgcn_mfma_f32_16x16x32_f16(*(const half8*)(lds + (size_t)(ks * 4 + g) * 1024 + (size_t)l * 16), bcs[ks], acc[g], 0, 0, 0);
            }
            #pragma unroll
            for (int ks = 0; ks < 22; ++ks) {
                #pragma unroll
                for (int g = 0; g < 4; ++g)
                    acc[g] = __builtin_amdgcn_mfma_f32_16x16x32_f16(*(const half8*)(lds + (size_t)((16 + ks) * 4 + g) * 1024 + (size_t)l * 16), bhs[ks], acc[g], 0, 0, 0);
            }
            // (F) lane-local epilogue: out + h2
            if (cc < OO) {
                const int u_ = t - 1;
                float cn[4], hn[4];
                #pragma unroll
                for (int r = 0; r < 4; ++r) {
                    const float ig = sigf(acc[0][r] + bs[r][0]);
                    const float fg = sigf(acc[1][r] + bs[r][1]);
                    const float gg = tanhf(acc[2][r] + bs[r][2]);
                    const float og = sigf(acc[3][r] + bs[r][3]);
                    const float c = fg * cr[r] + ig * gg;
                    cr[r] = c;
                    cn[r] = c; hn[r] = og * tanhf(c);
                }
                const f32x4 q = {cn[0], cn[1], cn[2], cn[3]};
                __builtin_nontemporal_store(q, (f32x4*)(out + (size_t)b * (TT * OO) + (size_t)u_ * OO + cc));
                char* h2w = wsb + H2S_OFF + (size_t)(t & 1) * H2SLAB;
                const size_t aoff = (size_t)((cc >> 5) * 4 + bfrag) * 1024
                                  + (size_t)((((cc >> 3) & 3) * 16 + lo)) * 16
                                  + (size_t)(cc & 7) * 2;
                astore8(h2w + aoff, pack4h(hn[0], hn[1], hn[2], hn[3]));
            }
            // (G) arrive (skip the final epoch; nobody waits on it)
            __syncthreads();
            if (t < TT && tid == 0) {
                const unsigned a2 = __hip_atomic_fetch_add(bar + L2CNT(grp), 1u, __ATOMIC_RELAXED, __HIP_MEMORY_SCOPE_AGENT);
                if (a2 == (unsigned)t * gsz - 1u) astore32(bar + L2FLG + grp, (unsigned)t);
            }
        }
    }
}

extern "C" void kernel_launch(void* const* d_in, const int* in_sizes, int n_in,
                              void* d_out, int out_size, void* d_ws, size_t ws_size,
                              hipStream_t stream)
{
    const float* data = (const float*)d_in[0];
    const float* Wih1 = (const float*)d_in[1];
    const float* Whh1 = (const float*)d_in[2];
    const float* bih1 = (const float*)d_in[3];
    const float* bhh1 = (const float*)d_in[4];
    const float* Wih2 = (const float*)d_in[5];
    const float* Whh2 = (const float*)d_in[6];
    const float* bih2 = (const float*)d_in[7];
    const float* bhh2 = (const float*)d_in[8];
    float* out = (float*)d_out;
    char* wsb  = (char*)d_ws;

    hipFuncSetAttribute((const void*)rnn_mfma, hipFuncAttributeMaxDynamicSharedMemorySize, (int)LDS_BYTES);
    hipMemsetAsync(wsb, 0, MEMSET_BYTES, stream);   // slabs + flags/counters: replay-safe
    rnn_mfma<<<NBLK, 256, LDS_BYTES, stream>>>(data,
                                               Wih1, Whh1, bih1, bhh1,
                                               Wih2, Whh2, bih2, bhh2,
                                               wsb, out);
}